// Round 1
// baseline (324.784 us; speedup 1.0000x reference)
//
#include <hip/hip_runtime.h>

#define P 128
#define GRID1 1024
#define BLK 256

__device__ __forceinline__ void atomicAddF(float* p, float v) {
#if defined(__HIP_DEVICE_COMPILE__)
    unsafeAtomicAdd(p, v);   // global_atomic_add_f32 on gfx950
#else
    atomicAdd(p, v);
#endif
}

// ws layout (floats): [0..127] colsum, [128..135] scalars
// scalars: 0:Sp_h 1:Sn_h 2:Sp_hc 3:Sn_hc 4:Sp_s 5:Sn_s 6:Sp_sc 7:Sn_sc

__global__ __launch_bounds__(BLK) void k_reduce(
        const float* __restrict__ muN,
        const float* __restrict__ h,  const float* __restrict__ hc,
        const float* __restrict__ s,  const float* __restrict__ sc,
        int n, float* __restrict__ ws)
{
    const int t  = threadIdx.x;
    const int c4 = t & 31;   // float4 column index (0..31)
    const int r  = t >> 5;   // row-within-group (0..7)

    // ---- column-sum of mu_N (N x 128), float4-coalesced ----
    const float4* mu4 = (const float4*)muN;
    float4 acc = make_float4(0.f, 0.f, 0.f, 0.f);
    for (long base = (long)blockIdx.x * 8; base < n; base += (long)gridDim.x * 8) {
        long row = base + r;
        if (row < n) {
            float4 v = mu4[row * 32 + c4];
            acc.x += v.x; acc.y += v.y; acc.z += v.z; acc.w += v.w;
        }
    }
    __shared__ float4 red[8][32];
    red[r][c4] = acc;
    __syncthreads();
    if (r < 4) {
        float4 o = red[r + 4][c4];
        red[r][c4].x += o.x; red[r][c4].y += o.y;
        red[r][c4].z += o.z; red[r][c4].w += o.w;
    }
    __syncthreads();
    if (r < 2) {
        float4 o = red[r + 2][c4];
        red[r][c4].x += o.x; red[r][c4].y += o.y;
        red[r][c4].z += o.z; red[r][c4].w += o.w;
    }
    __syncthreads();
    if (r == 0) {
        float4 a = red[0][c4];
        float4 b = red[1][c4];
        atomicAddF(&ws[c4 * 4 + 0], a.x + b.x);
        atomicAddF(&ws[c4 * 4 + 1], a.y + b.y);
        atomicAddF(&ws[c4 * 4 + 2], a.z + b.z);
        atomicAddF(&ws[c4 * 4 + 3], a.w + b.w);
    }

    // ---- relu-sum scalars for h, hc, s, sc ----
    float v8[8];
#pragma unroll
    for (int j = 0; j < 8; ++j) v8[j] = 0.f;
    int idx = blockIdx.x * BLK + t;          // grid covers N in one pass
    if (idx < n) {
        float vh  = h[idx],  vhc = hc[idx];
        float vs  = s[idx],  vsc = sc[idx];
        v8[0] = fmaxf(vh, 0.f);   v8[1] = fmaxf(-vh, 0.f);
        v8[2] = fmaxf(vhc, 0.f);  v8[3] = fmaxf(-vhc, 0.f);
        v8[4] = fmaxf(vs, 0.f);   v8[5] = fmaxf(-vs, 0.f);
        v8[6] = fmaxf(vsc, 0.f);  v8[7] = fmaxf(-vsc, 0.f);
    }
#pragma unroll
    for (int k = 32; k >= 1; k >>= 1) {
#pragma unroll
        for (int j = 0; j < 8; ++j) v8[j] += __shfl_xor(v8[j], k);
    }
    __shared__ float sred[4][8];
    int wave = t >> 6, lane = t & 63;
    if (lane == 0) {
#pragma unroll
        for (int j = 0; j < 8; ++j) sred[wave][j] = v8[j];
    }
    __syncthreads();
    if (t < 8) {
        float sum = sred[0][t] + sred[1][t] + sred[2][t] + sred[3][t];
        atomicAddF(&ws[P + t], sum);
    }
}

// One block, 256 threads: 5 matvecs (128x128) + W10@xi + relu.
__global__ __launch_bounds__(BLK) void k_final(
        const float* __restrict__ xi,
        const float* __restrict__ W1, const float* __restrict__ W2,
        const float* __restrict__ W3, const float* __restrict__ W4,
        const float* __restrict__ W5, const float* __restrict__ W6,
        const float* __restrict__ W7, const float* __restrict__ W8,
        const float* __restrict__ W9, const float* __restrict__ W10,
        const float* __restrict__ ws, float* __restrict__ out)
{
    const int t = threadIdx.x;
    __shared__ float xs[P];
    __shared__ float tmp[P];
    __shared__ float sc8[8];

    if (t < P) tmp[t] = 0.f;
    if (t < 8) sc8[t] = ws[P + t];

    const float* Wm[5]   = {W1, W2, W4, W6, W8};
    const float* wodd[5] = {nullptr, W3, W5, W7, W9};

    for (int m = 0; m < 5; ++m) {
        __syncthreads();
        if (t < P) {
            float x;
            if (m == 0) {
                x = ws[t];                       // colsum
            } else {
                float w = wodd[m][t];
                x = fmaxf(w, 0.f) * sc8[2 * (m - 1)]
                  + fmaxf(-w, 0.f) * sc8[2 * (m - 1) + 1];
            }
            xs[t] = x;
        }
        __syncthreads();

        const float4* W4p = (const float4*)Wm[m];
        const float4* xs4 = (const float4*)xs;
#pragma unroll
        for (int it = 0; it < 16; ++it) {
            int f   = it * BLK + t;        // float4 index into W (0..4095)
            int in4 = f & 31;              // float4 column
            int o   = f >> 5;              // output row (= it*8 + t/32)
            float4 w = W4p[f];
            float4 x = xs4[in4];
            float p = w.x * x.x + w.y * x.y + w.z * x.z + w.w * x.w;
#pragma unroll
            for (int k = 16; k >= 1; k >>= 1) p += __shfl_xor(p, k);
            if ((t & 31) == 0) tmp[o] += p;   // unique o per (wave,iter,matrix): race-free
        }
    }
    __syncthreads();
    if (t < P) {
        float v = tmp[t]
                + W10[t * 3 + 0] * xi[0]
                + W10[t * 3 + 1] * xi[1]
                + W10[t * 3 + 2] * xi[2];
        out[t] = fmaxf(v, 0.f);
    }
}

extern "C" void kernel_launch(void* const* d_in, const int* in_sizes, int n_in,
                              void* d_out, int out_size, void* d_ws, size_t ws_size,
                              hipStream_t stream) {
    const float* xi  = (const float*)d_in[0];
    const float* muN = (const float*)d_in[1];
    const float* h   = (const float*)d_in[2];
    const float* hc  = (const float*)d_in[3];
    const float* s   = (const float*)d_in[4];
    const float* sc  = (const float*)d_in[5];
    const float* W1  = (const float*)d_in[6];
    const float* W2  = (const float*)d_in[7];
    const float* W3  = (const float*)d_in[8];
    const float* W4  = (const float*)d_in[9];
    const float* W5  = (const float*)d_in[10];
    const float* W6  = (const float*)d_in[11];
    const float* W7  = (const float*)d_in[12];
    const float* W8  = (const float*)d_in[13];
    const float* W9  = (const float*)d_in[14];
    const float* W10 = (const float*)d_in[15];
    float* ws = (float*)d_ws;
    int n = in_sizes[2];   // 200000

    hipMemsetAsync(d_ws, 0, 1024, stream);   // zero colsum + scalars
    k_reduce<<<GRID1, BLK, 0, stream>>>(muN, h, hc, s, sc, n, ws);
    k_final<<<1, BLK, 0, stream>>>(xi, W1, W2, W3, W4, W5, W6, W7, W8, W9, W10,
                                   ws, (float*)d_out);
}